// Round 1
// baseline (3045.013 us; speedup 1.0000x reference)
//
#include <hip/hip_runtime.h>

// ---------------- types & helpers ----------------
typedef __attribute__((ext_vector_type(8))) short sh8;   // 8 bf16 (4 VGPRs)
typedef __attribute__((ext_vector_type(4))) float f32x4; // MFMA C/D

#define MFMA(a, b, c) __builtin_amdgcn_mfma_f32_16x16x32_bf16(a, b, c, 0, 0, 0)

__device__ __forceinline__ short f2bf(float f) {
    unsigned u = __builtin_bit_cast(unsigned, f);
    u += 0x7fffu + ((u >> 16) & 1u);   // RNE
    return (short)(u >> 16);
}
// packed f32x2 -> bf16x2 (RNE), no builtin on gfx950 (learn_hip m240)
__device__ __forceinline__ unsigned pk_bf16(float lo, float hi) {
    unsigned r;
    asm("v_cvt_pk_bf16_f32 %0, %1, %2" : "=v"(r) : "v"(lo), "v"(hi));
    return r;
}

// Problem constants
#define B_   16384
#define NW   256
#define NT   49      // tokens per window
#define DIM  128
#define HEADS 4
#define HD   32
#define SCALE 0.17677669529663687f   // 32^-0.5

// ws layout (bytes)
#define V_BYTES     205520896u           // [B_][H][49][32] bf16
#define AMASK_OFF   205520896u           // [H][NW][64][64] fp32 = 16,777,216
#define QW_OFF      222298112u           // [384][128] bf16 = 98,304
#define PW_OFF      222396416u           // [128][128] bf16 = 32,768
// total: 222,429,184 bytes

// ---------------- kernel 1: precompute ----------------
// amask[h][wi][r][c] = bias(h,r,c) + mask(wi,r,c), with -1e30 for c>=49 (softmax pad),
// 0 padding for r>=49 (rows unused but must stay finite).
__global__ __launch_bounds__(256) void wa_prep(
    const float* __restrict__ mask, const float* __restrict__ rpb,
    const int* __restrict__ rpi, const float* __restrict__ qkv_w,
    const float* __restrict__ proj_w, float* __restrict__ amask,
    short* __restrict__ qw, short* __restrict__ pw) {
    int g = blockIdx.x * 256 + threadIdx.x;  // 4,194,304 total
    int c = g & 63, r = (g >> 6) & 63, wi = (g >> 12) & 255, h = g >> 20;
    float v;
    if (c < NT) {
        v = 0.f;
        if (r < NT) {
            int idx = r * NT + c;
            v = rpb[rpi[idx] * HEADS + h] + mask[wi * (NT * NT) + idx];
        }
    } else {
        v = -1e30f;
    }
    amask[g] = v;
    if (g < 384 * 128) qw[g] = f2bf(qkv_w[g]);
    if (g < 128 * 128) pw[g] = f2bf(proj_w[g]);
}

// ---------------- kernel 2: qkv projection GEMM (sel-merged) ----------------
// One block per 128-token tile; stages x ONCE, loops sel=q,k,v. Weight B-fragments
// come straight from global (98 KB total, L2-resident) -> no lB tile, LDS=38 KB ->
// 4 blocks/CU, and x is fetched from HBM exactly once (was 3x across sel-blocks).
__global__ __launch_bounds__(256, 4) void wa_qkv(
    const float* __restrict__ x, const short* __restrict__ qw,
    const float* __restrict__ qkv_b, short* __restrict__ qk,
    short* __restrict__ vbuf) {
    __shared__ short lA[128 * 152];  // x tile bf16, pad-stride 152
    const int tid = threadIdx.x;
    const int bm = blockIdx.x;
    {
        const float* xb = x + (size_t)bm * (128 * 128);
#pragma unroll
        for (int i = 0; i < 8; i++) {
            int chunk = i * 256 + tid;            // 2048 chunks of 8 elements
            int row = chunk >> 4, col = (chunk & 15) * 8;
            float4 v0 = *(const float4*)(xb + row * 128 + col);
            float4 v1 = *(const float4*)(xb + row * 128 + col + 4);
            uint4 u;
            u.x = pk_bf16(v0.x, v0.y); u.y = pk_bf16(v0.z, v0.w);
            u.z = pk_bf16(v1.x, v1.y); u.w = pk_bf16(v1.z, v1.w);
            *(uint4*)(&lA[row * 152 + col]) = u;
        }
    }
    __syncthreads();

    const int lane = tid & 63, wid = tid >> 6;
    const int quad = lane >> 4, l15 = lane & 15;
    const int wm = (wid & 1) * 64, wn = (wid >> 1) * 64;

#pragma unroll 1
    for (int sel = 0; sel < 3; sel++) {
        const short* wb = qw + sel * (128 * 128);
        f32x4 acc[4][4] = {};
#pragma unroll
        for (int ks = 0; ks < 4; ks++) {
            sh8 a[4], b[4];
#pragma unroll
            for (int t = 0; t < 4; t++)
                a[t] = *(const sh8*)(&lA[(wm + t * 16 + l15) * 152 + ks * 32 + quad * 8]);
#pragma unroll
            for (int t = 0; t < 4; t++)
                b[t] = *(const sh8*)(wb + (wn + t * 16 + l15) * 128 + ks * 32 + quad * 8);
#pragma unroll
            for (int ti = 0; ti < 4; ti++)
#pragma unroll
                for (int tj = 0; tj < 4; tj++)
                    acc[ti][tj] = MFMA(a[ti], b[tj], acc[ti][tj]);
        }
        // epilogue: scatter to q/k (in d_out) or v (ws) as bf16
        float bv[4]; int hh[4], ee[4];
#pragma unroll
        for (int tj = 0; tj < 4; tj++) {
            int n = wn + tj * 16 + l15;
            bv[tj] = qkv_b[sel * 128 + n];
            hh[tj] = n >> 5; ee[tj] = n & 31;
        }
        short* outp = (sel < 2) ? qk : vbuf;
#pragma unroll
        for (int ti = 0; ti < 4; ti++)
#pragma unroll
            for (int reg = 0; reg < 4; reg++) {
                int t = bm * 128 + wm + ti * 16 + quad * 4 + reg;  // C row = quad*4+reg
                unsigned bwin = (unsigned)t / 49u;
                int nn = t - bwin * 49u;
#pragma unroll
                for (int tj = 0; tj < 4; tj++) {
                    float v = acc[ti][tj][reg] + bv[tj];
                    if (sel == 0) v *= SCALE;
                    size_t dst;
                    if (sel < 2)
                        dst = (size_t)bwin * 12544 + (size_t)sel * 6272 +
                              (size_t)(hh[tj] * NT + nn) * HD + ee[tj];
                    else
                        dst = (((size_t)bwin * HEADS + hh[tj]) * NT + nn) * HD + ee[tj];
                    outp[dst] = f2bf(v);
                }
            }
    }
}

// ---------------- kernel 3: fused attention + proj (swapped-QK^T) ----------------
// S^T = K Q^T (MFMA) puts the k reduction axis in-lane: softmax = VALU tree + 4
// shuffles per q-block; amask loads become float4; P reaches LDS via cvt_pk +
// ds_write_b64. All LDS tiles are zero-pad stride-64/128 with XOR swizzle
// (idx ^= (row&7)<<3) -> 49152 B/block -> 3 blocks/CU.
// out bytes for window b == q,k bytes for window b: all q,k reads complete before
// the two __syncthreads() that precede the epilogue, so overwrite is safe.
__global__ __launch_bounds__(256, 3) void wa_attn(
    const short* __restrict__ qk, const short* __restrict__ vbuf,
    const float* __restrict__ amask, const short* __restrict__ pw,
    const float* __restrict__ proj_b, float* __restrict__ out) {
    __shared__ short smem[24576];  // shorts: [0,16384) P 4x[64][64] swz; ctx [64][128] aliases
                                   //         [16384,24576) V^T 4x[32][64] swz
    const int tid = threadIdx.x, lane = tid & 63, wid = tid >> 6;
    const int quad = lane >> 4, l15 = lane & 15;
    const int b = blockIdx.x, wi = b & 255;
    short* Pl = smem + wid * 4096;
    short* Vl = smem + 16384 + wid * 2048;
    const int swz = (l15 & 7) << 3;   // row-XOR swizzle term for rows == *16+l15

    // V^T staging: Vl[e][tok ^ ((e&7)<<3)], zero-padded tokens 49..63
    {
        const short* vb = vbuf + ((size_t)b * HEADS + wid) * (NT * HD);
#pragma unroll
        for (int i = 0; i < 4; i++) {
            int chunk = i * 64 + lane;            // token=chunk>>2, colc=(chunk&3)*8
            int token = chunk >> 2, colc = (chunk & 3) * 8;
            sh8 v = (sh8)(short)0;
            if (token < NT) v = *(const sh8*)(vb + token * HD + colc);
#pragma unroll
            for (int j = 0; j < 8; j++)
                Vl[(colc + j) * 64 + (token ^ (j << 3))] = v[j];   // (e&7)==j
        }
    }

    // Q,K fragments straight from global (token<49 predicated)
    const short* qb = qk + (size_t)b * 12544 + wid * (NT * HD);
    const short* kb = qb + 6272;
    sh8 aq[4], bk[4];
#pragma unroll
    for (int t = 0; t < 4; t++) {
        int tok = t * 16 + l15;
        sh8 z = (sh8)(short)0;
        aq[t] = z; bk[t] = z;
        if (tok < NT) {
            aq[t] = *(const sh8*)(qb + tok * HD + quad * 8);
            bk[t] = *(const sh8*)(kb + tok * HD + quad * 8);
        }
    }
    // S^T = K Q^T : row k = ti*16+quad*4+reg, col q = tj*16+l15
    f32x4 S[4][4] = {};
#pragma unroll
    for (int ti = 0; ti < 4; ti++)
#pragma unroll
        for (int tj = 0; tj < 4; tj++) S[ti][tj] = MFMA(bk[ti], aq[tj], S[ti][tj]);

    // softmax: reduction over k = in-lane (16 regs) + shfl_xor(16,32) across quads
    const float* am = amask + (((size_t)wid * NW + wi) << 12);
#pragma unroll
    for (int tj = 0; tj < 4; tj++) {
        const int q = tj * 16 + l15;
        float mx = -1e38f;
#pragma unroll
        for (int ti = 0; ti < 4; ti++) {
            float4 m4 = *(const float4*)(am + q * 64 + ti * 16 + quad * 4);
            S[ti][tj][0] += m4.x; S[ti][tj][1] += m4.y;
            S[ti][tj][2] += m4.z; S[ti][tj][3] += m4.w;
#pragma unroll
            for (int r = 0; r < 4; r++) mx = fmaxf(mx, S[ti][tj][r]);
        }
        mx = fmaxf(mx, __shfl_xor(mx, 16));
        mx = fmaxf(mx, __shfl_xor(mx, 32));
        float sum = 0.f;
#pragma unroll
        for (int ti = 0; ti < 4; ti++)
#pragma unroll
            for (int r = 0; r < 4; r++) {
                float p = __expf(S[ti][tj][r] - mx);
                S[ti][tj][r] = p;
                sum += p;
            }
        sum += __shfl_xor(sum, 16);
        sum += __shfl_xor(sum, 32);
        float inv = 1.f / sum;
        // normalized P -> LDS, 4 consecutive k per lane -> b64 writes (swizzled)
        short* pq = Pl + q * 64;                  // q&7 == l15&7 -> swz valid
#pragma unroll
        for (int ti = 0; ti < 4; ti++) {
            uint2 u;
            u.x = pk_bf16(S[ti][tj][0] * inv, S[ti][tj][1] * inv);
            u.y = pk_bf16(S[ti][tj][2] * inv, S[ti][tj][3] * inv);
            *(uint2*)(pq + ((ti * 16 + quad * 4) ^ swz)) = u;
        }
    }

    // PV: A = P[64x64], B = V^T[32x64] (same-wave LDS dep: lgkmcnt only, no barrier)
    f32x4 CV[4][2] = {};
#pragma unroll
    for (int ks = 0; ks < 2; ks++) {
        sh8 pa[4], vv[2];
#pragma unroll
        for (int t = 0; t < 4; t++)
            pa[t] = *(const sh8*)(Pl + (t * 16 + l15) * 64 + ((ks * 32 + quad * 8) ^ swz));
#pragma unroll
        for (int t = 0; t < 2; t++)
            vv[t] = *(const sh8*)(Vl + (t * 16 + l15) * 64 + ((ks * 32 + quad * 8) ^ swz));
#pragma unroll
        for (int ti = 0; ti < 4; ti++)
#pragma unroll
            for (int tj = 0; tj < 2; tj++) CV[ti][tj] = MFMA(pa[ti], vv[tj], CV[ti][tj]);
    }

    __syncthreads();  // all waves done reading P/V before ctx aliases P region

    // ctx [64][128] swizzled; wave writes its head's 32 cols (normalization already in P)
#pragma unroll
    for (int ti = 0; ti < 4; ti++)
#pragma unroll
        for (int reg = 0; reg < 4; reg++) {
            int row = ti * 16 + quad * 4 + reg;
            int rs = (row & 7) << 3;
#pragma unroll
            for (int tj = 0; tj < 2; tj++)
                smem[row * 128 + ((wid * 32 + tj * 16 + l15) ^ rs)] = f2bf(CV[ti][tj][reg]);
        }
    __syncthreads();

    // proj: wave computes douts [wid*32, wid*32+32), full K=128
    f32x4 O[4][2] = {};
    const short* pwb = pw + (wid * 32) * 128;
#pragma unroll
    for (int ks = 0; ks < 4; ks++) {
        sh8 ca[4], wb2[2];
#pragma unroll
        for (int t = 0; t < 4; t++)
            ca[t] = *(const sh8*)(&smem[(t * 16 + l15) * 128 + ((ks * 32 + quad * 8) ^ swz)]);
#pragma unroll
        for (int t = 0; t < 2; t++)
            wb2[t] = *(const sh8*)(pwb + (t * 16 + l15) * 128 + ks * 32 + quad * 8);
#pragma unroll
        for (int ti = 0; ti < 4; ti++)
#pragma unroll
            for (int tj = 0; tj < 2; tj++) O[ti][tj] = MFMA(ca[ti], wb2[tj], O[ti][tj]);
    }
    float pb[2];
#pragma unroll
    for (int t = 0; t < 2; t++) pb[t] = proj_b[wid * 32 + t * 16 + l15];
    float* ob = out + (size_t)b * (NT * DIM);
#pragma unroll
    for (int ti = 0; ti < 4; ti++)
#pragma unroll
        for (int reg = 0; reg < 4; reg++) {
            int row = ti * 16 + quad * 4 + reg;
            if (row < NT) {
#pragma unroll
                for (int tj = 0; tj < 2; tj++)
                    ob[row * DIM + wid * 32 + tj * 16 + l15] = O[ti][tj][reg] + pb[tj];
            }
        }
}

// ---------------- launcher ----------------
extern "C" void kernel_launch(void* const* d_in, const int* in_sizes, int n_in,
                              void* d_out, int out_size, void* d_ws, size_t ws_size,
                              hipStream_t stream) {
    const float* x      = (const float*)d_in[0];
    const float* mask   = (const float*)d_in[1];
    const float* qkv_w  = (const float*)d_in[2];
    const float* qkv_b  = (const float*)d_in[3];
    const float* proj_w = (const float*)d_in[4];
    const float* proj_b = (const float*)d_in[5];
    const float* rpb    = (const float*)d_in[6];
    const int*   rpi    = (const int*)d_in[7];

    char* ws = (char*)d_ws;
    short* vbuf  = (short*)ws;
    float* amask = (float*)(ws + AMASK_OFF);
    short* qw    = (short*)(ws + QW_OFF);
    short* pw    = (short*)(ws + PW_OFF);
    short* qkbuf = (short*)d_out;   // q,k live inside d_out (exact byte overlap per window)
    float* out   = (float*)d_out;

    wa_prep<<<16384, 256, 0, stream>>>(mask, rpb, rpi, qkv_w, proj_w, amask, qw, pw);
    wa_qkv<<<6272, 256, 0, stream>>>(x, qw, qkv_b, qkbuf, vbuf);
    wa_attn<<<B_, 256, 0, stream>>>(qkbuf, vbuf, amask, pw, proj_b, out);
}

// Round 2
// 2071.670 us; speedup vs baseline: 1.4698x; 1.4698x over previous
//
#include <hip/hip_runtime.h>

// ---------------- types & helpers ----------------
typedef __attribute__((ext_vector_type(8))) short sh8;   // 8 bf16 (4 VGPRs)
typedef __attribute__((ext_vector_type(4))) float f32x4; // MFMA C/D

#define MFMA(a, b, c) __builtin_amdgcn_mfma_f32_16x16x32_bf16(a, b, c, 0, 0, 0)

__device__ __forceinline__ short f2bf(float f) {
    unsigned u = __builtin_bit_cast(unsigned, f);
    u += 0x7fffu + ((u >> 16) & 1u);   // RNE
    return (short)(u >> 16);
}
// packed f32x2 -> bf16x2 (RNE), no builtin on gfx950 (learn_hip m240)
__device__ __forceinline__ unsigned pk_bf16(float lo, float hi) {
    unsigned r;
    asm("v_cvt_pk_bf16_f32 %0, %1, %2" : "=v"(r) : "v"(lo), "v"(hi));
    return r;
}

// Problem constants
#define B_   16384
#define NW   256
#define NT   49      // tokens per window
#define DIM  128
#define HEADS 4
#define HD   32
#define SCALE 0.17677669529663687f   // 32^-0.5

// ws layout (bytes)
#define V_BYTES     205520896u           // [B_][H][49][32] bf16
#define AMASK_OFF   205520896u           // [H][NW][64][64] fp32 = 16,777,216
#define QW_OFF      222298112u           // [384][128] bf16 = 98,304
#define PW_OFF      222396416u           // [128][128] bf16 = 32,768
// total: 222,429,184 bytes

// ---------------- kernel 1: precompute ----------------
// amask[h][wi][r][c] = bias(h,r,c) + mask(wi,r,c), with -1e30 for c>=49 (softmax pad),
// 0 padding for r>=49 (rows unused but must stay finite).
__global__ __launch_bounds__(256) void wa_prep(
    const float* __restrict__ mask, const float* __restrict__ rpb,
    const int* __restrict__ rpi, const float* __restrict__ qkv_w,
    const float* __restrict__ proj_w, float* __restrict__ amask,
    short* __restrict__ qw, short* __restrict__ pw) {
    int g = blockIdx.x * 256 + threadIdx.x;  // 4,194,304 total
    int c = g & 63, r = (g >> 6) & 63, wi = (g >> 12) & 255, h = g >> 20;
    float v;
    if (c < NT) {
        v = 0.f;
        if (r < NT) {
            int idx = r * NT + c;
            v = rpb[rpi[idx] * HEADS + h] + mask[wi * (NT * NT) + idx];
        }
    } else {
        v = -1e30f;
    }
    amask[g] = v;
    if (g < 384 * 128) qw[g] = f2bf(qkv_w[g]);
    if (g < 128 * 128) pw[g] = f2bf(proj_w[g]);
}

// ---------------- kernel 2: qkv projection GEMM (sel-merged) ----------------
// One block per 128-token tile; stages x ONCE, loops sel=q,k,v. Weight B-fragments
// come straight from global (98 KB total, L2-resident) -> no lB tile; x fetched
// from HBM exactly once (was 3x across sel-blocks in baseline).
// __launch_bounds__(256, 2): the live set (acc 64 + operands 32 + addr) needs
// ~150-170 unified VGPR+AGPR. (256,4) caps at 128 -> acc spills to scratch ->
// 6.7 GB HBM traffic, 2272 us (round-1 regression). Keep min-waves at 2.
__global__ __launch_bounds__(256, 2) void wa_qkv(
    const float* __restrict__ x, const short* __restrict__ qw,
    const float* __restrict__ qkv_b, short* __restrict__ qk,
    short* __restrict__ vbuf) {
    __shared__ short lA[128 * 152];  // x tile bf16, pad-stride 152
    const int tid = threadIdx.x;
    const int bm = blockIdx.x;
    {
        const float* xb = x + (size_t)bm * (128 * 128);
#pragma unroll
        for (int i = 0; i < 8; i++) {
            int chunk = i * 256 + tid;            // 2048 chunks of 8 elements
            int row = chunk >> 4, col = (chunk & 15) * 8;
            float4 v0 = *(const float4*)(xb + row * 128 + col);
            float4 v1 = *(const float4*)(xb + row * 128 + col + 4);
            uint4 u;
            u.x = pk_bf16(v0.x, v0.y); u.y = pk_bf16(v0.z, v0.w);
            u.z = pk_bf16(v1.x, v1.y); u.w = pk_bf16(v1.z, v1.w);
            *(uint4*)(&lA[row * 152 + col]) = u;
        }
    }
    __syncthreads();

    const int lane = tid & 63, wid = tid >> 6;
    const int quad = lane >> 4, l15 = lane & 15;
    const int wm = (wid & 1) * 64, wn = (wid >> 1) * 64;

#pragma unroll 1
    for (int sel = 0; sel < 3; sel++) {
        const short* wb = qw + sel * (128 * 128);
        f32x4 acc[4][4] = {};
#pragma unroll
        for (int ks = 0; ks < 4; ks++) {
            sh8 a[4], b[4];
#pragma unroll
            for (int t = 0; t < 4; t++)
                a[t] = *(const sh8*)(&lA[(wm + t * 16 + l15) * 152 + ks * 32 + quad * 8]);
#pragma unroll
            for (int t = 0; t < 4; t++)
                b[t] = *(const sh8*)(wb + (wn + t * 16 + l15) * 128 + ks * 32 + quad * 8);
#pragma unroll
            for (int ti = 0; ti < 4; ti++)
#pragma unroll
                for (int tj = 0; tj < 4; tj++)
                    acc[ti][tj] = MFMA(a[ti], b[tj], acc[ti][tj]);
        }
        // epilogue: scatter to q/k (in d_out) or v (ws) as bf16
        float bv[4]; int hh[4], ee[4];
#pragma unroll
        for (int tj = 0; tj < 4; tj++) {
            int n = wn + tj * 16 + l15;
            bv[tj] = qkv_b[sel * 128 + n];
            hh[tj] = n >> 5; ee[tj] = n & 31;
        }
        short* outp = (sel < 2) ? qk : vbuf;
#pragma unroll
        for (int ti = 0; ti < 4; ti++)
#pragma unroll
            for (int reg = 0; reg < 4; reg++) {
                int t = bm * 128 + wm + ti * 16 + quad * 4 + reg;  // C row = quad*4+reg
                unsigned bwin = (unsigned)t / 49u;
                int nn = t - bwin * 49u;
#pragma unroll
                for (int tj = 0; tj < 4; tj++) {
                    float v = acc[ti][tj][reg] + bv[tj];
                    if (sel == 0) v *= SCALE;
                    size_t dst;
                    if (sel < 2)
                        dst = (size_t)bwin * 12544 + (size_t)sel * 6272 +
                              (size_t)(hh[tj] * NT + nn) * HD + ee[tj];
                    else
                        dst = (((size_t)bwin * HEADS + hh[tj]) * NT + nn) * HD + ee[tj];
                    outp[dst] = f2bf(v);
                }
            }
    }
}

// ---------------- kernel 3: fused attention + proj (swapped-QK^T) ----------------
// S^T = K Q^T (MFMA) puts the k reduction axis in-lane: softmax = VALU tree + 4
// shuffles per q-block; amask loads become float4; P reaches LDS via cvt_pk +
// ds_write_b64. All LDS tiles are zero-pad stride-64/128 with XOR swizzle
// (idx ^= (row&7)<<3) -> 49152 B/block -> 3 blocks/CU.
// out bytes for window b == q,k bytes for window b: all q,k reads complete before
// the two __syncthreads() that precede the epilogue, so overwrite is safe.
__global__ __launch_bounds__(256, 3) void wa_attn(
    const short* __restrict__ qk, const short* __restrict__ vbuf,
    const float* __restrict__ amask, const short* __restrict__ pw,
    const float* __restrict__ proj_b, float* __restrict__ out) {
    __shared__ short smem[24576];  // shorts: [0,16384) P 4x[64][64] swz; ctx [64][128] aliases
                                   //         [16384,24576) V^T 4x[32][64] swz
    const int tid = threadIdx.x, lane = tid & 63, wid = tid >> 6;
    const int quad = lane >> 4, l15 = lane & 15;
    const int b = blockIdx.x, wi = b & 255;
    short* Pl = smem + wid * 4096;
    short* Vl = smem + 16384 + wid * 2048;
    const int swz = (l15 & 7) << 3;   // row-XOR swizzle term for rows == *16+l15

    // V^T staging: Vl[e][tok ^ ((e&7)<<3)], zero-padded tokens 49..63
    {
        const short* vb = vbuf + ((size_t)b * HEADS + wid) * (NT * HD);
#pragma unroll
        for (int i = 0; i < 4; i++) {
            int chunk = i * 64 + lane;            // token=chunk>>2, colc=(chunk&3)*8
            int token = chunk >> 2, colc = (chunk & 3) * 8;
            sh8 v = (sh8)(short)0;
            if (token < NT) v = *(const sh8*)(vb + token * HD + colc);
#pragma unroll
            for (int j = 0; j < 8; j++)
                Vl[(colc + j) * 64 + (token ^ (j << 3))] = v[j];   // (e&7)==j
        }
    }

    // Q,K fragments straight from global (token<49 predicated)
    const short* qb = qk + (size_t)b * 12544 + wid * (NT * HD);
    const short* kb = qb + 6272;
    sh8 aq[4], bk[4];
#pragma unroll
    for (int t = 0; t < 4; t++) {
        int tok = t * 16 + l15;
        sh8 z = (sh8)(short)0;
        aq[t] = z; bk[t] = z;
        if (tok < NT) {
            aq[t] = *(const sh8*)(qb + tok * HD + quad * 8);
            bk[t] = *(const sh8*)(kb + tok * HD + quad * 8);
        }
    }
    // S^T = K Q^T : row k = ti*16+quad*4+reg, col q = tj*16+l15
    f32x4 S[4][4] = {};
#pragma unroll
    for (int ti = 0; ti < 4; ti++)
#pragma unroll
        for (int tj = 0; tj < 4; tj++) S[ti][tj] = MFMA(bk[ti], aq[tj], S[ti][tj]);

    // softmax: reduction over k = in-lane (16 regs) + shfl_xor(16,32) across quads
    const float* am = amask + (((size_t)wid * NW + wi) << 12);
#pragma unroll
    for (int tj = 0; tj < 4; tj++) {
        const int q = tj * 16 + l15;
        float mx = -1e38f;
#pragma unroll
        for (int ti = 0; ti < 4; ti++) {
            float4 m4 = *(const float4*)(am + q * 64 + ti * 16 + quad * 4);
            S[ti][tj][0] += m4.x; S[ti][tj][1] += m4.y;
            S[ti][tj][2] += m4.z; S[ti][tj][3] += m4.w;
#pragma unroll
            for (int r = 0; r < 4; r++) mx = fmaxf(mx, S[ti][tj][r]);
        }
        mx = fmaxf(mx, __shfl_xor(mx, 16));
        mx = fmaxf(mx, __shfl_xor(mx, 32));
        float sum = 0.f;
#pragma unroll
        for (int ti = 0; ti < 4; ti++)
#pragma unroll
            for (int r = 0; r < 4; r++) {
                float p = __expf(S[ti][tj][r] - mx);
                S[ti][tj][r] = p;
                sum += p;
            }
        sum += __shfl_xor(sum, 16);
        sum += __shfl_xor(sum, 32);
        float inv = 1.f / sum;
        // normalized P -> LDS, 4 consecutive k per lane -> b64 writes (swizzled)
        short* pq = Pl + q * 64;                  // q&7 == l15&7 -> swz valid
#pragma unroll
        for (int ti = 0; ti < 4; ti++) {
            uint2 u;
            u.x = pk_bf16(S[ti][tj][0] * inv, S[ti][tj][1] * inv);
            u.y = pk_bf16(S[ti][tj][2] * inv, S[ti][tj][3] * inv);
            *(uint2*)(pq + ((ti * 16 + quad * 4) ^ swz)) = u;
        }
    }

    // PV: A = P[64x64], B = V^T[32x64] (same-wave LDS dep: lgkmcnt only, no barrier)
    f32x4 CV[4][2] = {};
#pragma unroll
    for (int ks = 0; ks < 2; ks++) {
        sh8 pa[4], vv[2];
#pragma unroll
        for (int t = 0; t < 4; t++)
            pa[t] = *(const sh8*)(Pl + (t * 16 + l15) * 64 + ((ks * 32 + quad * 8) ^ swz));
#pragma unroll
        for (int t = 0; t < 2; t++)
            vv[t] = *(const sh8*)(Vl + (t * 16 + l15) * 64 + ((ks * 32 + quad * 8) ^ swz));
#pragma unroll
        for (int ti = 0; ti < 4; ti++)
#pragma unroll
            for (int tj = 0; tj < 2; tj++) CV[ti][tj] = MFMA(pa[ti], vv[tj], CV[ti][tj]);
    }

    __syncthreads();  // all waves done reading P/V before ctx aliases P region

    // ctx [64][128] swizzled; wave writes its head's 32 cols (normalization already in P)
#pragma unroll
    for (int ti = 0; ti < 4; ti++)
#pragma unroll
        for (int reg = 0; reg < 4; reg++) {
            int row = ti * 16 + quad * 4 + reg;
            int rs = (row & 7) << 3;
#pragma unroll
            for (int tj = 0; tj < 2; tj++)
                smem[row * 128 + ((wid * 32 + tj * 16 + l15) ^ rs)] = f2bf(CV[ti][tj][reg]);
        }
    __syncthreads();

    // proj: wave computes douts [wid*32, wid*32+32), full K=128
    f32x4 O[4][2] = {};
    const short* pwb = pw + (wid * 32) * 128;
#pragma unroll
    for (int ks = 0; ks < 4; ks++) {
        sh8 ca[4], wb2[2];
#pragma unroll
        for (int t = 0; t < 4; t++)
            ca[t] = *(const sh8*)(&smem[(t * 16 + l15) * 128 + ((ks * 32 + quad * 8) ^ swz)]);
#pragma unroll
        for (int t = 0; t < 2; t++)
            wb2[t] = *(const sh8*)(pwb + (t * 16 + l15) * 128 + ks * 32 + quad * 8);
#pragma unroll
        for (int ti = 0; ti < 4; ti++)
#pragma unroll
            for (int tj = 0; tj < 2; tj++) O[ti][tj] = MFMA(ca[ti], wb2[tj], O[ti][tj]);
    }
    float pb[2];
#pragma unroll
    for (int t = 0; t < 2; t++) pb[t] = proj_b[wid * 32 + t * 16 + l15];
    float* ob = out + (size_t)b * (NT * DIM);
#pragma unroll
    for (int ti = 0; ti < 4; ti++)
#pragma unroll
        for (int reg = 0; reg < 4; reg++) {
            int row = ti * 16 + quad * 4 + reg;
            if (row < NT) {
#pragma unroll
                for (int tj = 0; tj < 2; tj++)
                    ob[row * DIM + wid * 32 + tj * 16 + l15] = O[ti][tj][reg] + pb[tj];
            }
        }
}

// ---------------- launcher ----------------
extern "C" void kernel_launch(void* const* d_in, const int* in_sizes, int n_in,
                              void* d_out, int out_size, void* d_ws, size_t ws_size,
                              hipStream_t stream) {
    const float* x      = (const float*)d_in[0];
    const float* mask   = (const float*)d_in[1];
    const float* qkv_w  = (const float*)d_in[2];
    const float* qkv_b  = (const float*)d_in[3];
    const float* proj_w = (const float*)d_in[4];
    const float* proj_b = (const float*)d_in[5];
    const float* rpb    = (const float*)d_in[6];
    const int*   rpi    = (const int*)d_in[7];

    char* ws = (char*)d_ws;
    short* vbuf  = (short*)ws;
    float* amask = (float*)(ws + AMASK_OFF);
    short* qw    = (short*)(ws + QW_OFF);
    short* pw    = (short*)(ws + PW_OFF);
    short* qkbuf = (short*)d_out;   // q,k live inside d_out (exact byte overlap per window)
    float* out   = (float*)d_out;

    wa_prep<<<16384, 256, 0, stream>>>(mask, rpb, rpi, qkv_w, proj_w, amask, qw, pw);
    wa_qkv<<<6272, 256, 0, stream>>>(x, qw, qkv_b, qkbuf, vbuf);
    wa_attn<<<B_, 256, 0, stream>>>(qkbuf, vbuf, amask, pw, proj_b, out);
}